// Round 6
// baseline (416.993 us; speedup 1.0000x reference)
//
#include <hip/hip_runtime.h>

// Problem constants (match reference setup_inputs)
#define GH 720
#define GW 1280
#define GT 20
#define GB 8
#define NEV 500000

// Spatial tile: TY rows x TX cols, full T depth -> 20*8*64*4B = 40 KB LDS
#define TY 8
#define TX 64
#define NTY (GH / TY)            // 90
#define NTX (GW / TX)            // 20
#define NBINS (GB * NTY * NTX)   // 14400
#define CAP 512                  // avg load ~208, Poisson max ~360 -> safe (+ overflow path)
#define OVF_CAP (1u << 20)

typedef float vfloat4 __attribute__((ext_vector_type(4)));   // clang vector for nontemporal builtins

// ---------------- Phase 0: zero bin counters + overflow counter ----------------
__global__ __launch_bounds__(256) void k_zero(unsigned* __restrict__ cnt)
{
    int i = blockIdx.x * blockDim.x + threadIdx.x;
    if (i < NBINS + 1) cnt[i] = 0u;   // cnt[NBINS] is ovfcnt
}

// ---------------- Phase 1: single-pass bucket scatter ----------------
// record: word0 = x | y<<11 | p<<21 | k0c<<22 | b<<27 ; word1 = w1 bits
__global__ __launch_bounds__(256) void k_bucket(
    const float4* __restrict__ ev, const int* __restrict__ counts,
    unsigned* __restrict__ cnt, uint2* __restrict__ buckets,
    uint2* __restrict__ ovf)
{
    int i = blockIdx.x * blockDim.x + threadIdx.x;
    if (i >= GB * NEV) return;
    int b = i / NEV;                    // constant divisor -> magic-mul
    int n = i - b * NEV;
    if (n >= counts[b]) return;

    float4 e = ev[i];
    int x = min(max((int)e.x, 0), GW - 1);
    int y = min(max((int)e.y, 0), GH - 1);
    int bin = (b * NTY + (y >> 3)) * NTX + (x >> 6);

    float tb = e.z * (float)(GT - 1);
    int k0 = (int)floorf(tb);
    float w1 = tb - (float)k0;          // before clamping, matches reference
    int k0c = min(max(k0, 0), GT - 1);
    unsigned p = (e.w > 0.5f) ? 1u : 0u;

    unsigned word0 = (unsigned)x | ((unsigned)y << 11) | (p << 21)
                   | ((unsigned)k0c << 22) | ((unsigned)b << 27);
    uint2 rec = make_uint2(word0, __float_as_uint(w1));

    unsigned pos = atomicAdd(&cnt[bin], 1u);
    if (pos < CAP) {
        buckets[(size_t)bin * CAP + pos] = rec;
    } else {
        unsigned o = atomicAdd(&cnt[NBINS], 1u);
        if (o < OVF_CAP) ovf[o] = rec;
    }
}

// ---------------- Phase 2: per-tile LDS accumulate + full-tile write ----------------
__global__ __launch_bounds__(256) void k_accum(
    const uint2* __restrict__ buckets, const unsigned* __restrict__ cnt,
    float* __restrict__ out)
{
    __shared__ float tile[GT * TY * TX];     // 10240 floats = 40 KB
    int bin = blockIdx.x;
    int tid = threadIdx.x;

    vfloat4* t4z = (vfloat4*)tile;
    for (int j = tid; j < GT * TY * (TX / 4); j += 256) t4z[j] = (vfloat4){0.f, 0.f, 0.f, 0.f};
    __syncthreads();

    unsigned m = min(cnt[bin], (unsigned)CAP);
    const uint2* bp = buckets + (size_t)bin * CAP;
    for (unsigned idx = tid; idx < m; idx += 256) {
        uint2 r = bp[idx];
        int x  = r.x & 2047;
        int y  = (r.x >> 11) & 1023;
        int p  = (r.x >> 21) & 1;
        int k0 = (r.x >> 22) & 31;
        float w1 = __uint_as_float(r.y);
        float w0 = 1.0f - w1;
        float pol = p ? 1.0f : -1.0f;
        int k1 = min(k0 + 1, GT - 1);
        int yy = y & (TY - 1);
        int xx = x & (TX - 1);
        atomicAdd(&tile[(k0 * TY + yy) * TX + xx], pol * w0);
        atomicAdd(&tile[(k1 * TY + yy) * TX + xx], pol * w1);
    }
    __syncthreads();

    // decompose bin -> (b, ty, tx)
    int tx = bin % NTX;
    int rem = bin / NTX;
    int ty = rem % NTY;
    int b  = rem / NTY;
    int y0 = ty * TY;
    int x0 = tx * TX;

    const vfloat4* t4 = (const vfloat4*)tile;
    vfloat4* o4 = (vfloat4*)out;
    // 2560 float4 per tile; 16 float4 per (k,yy) row of 64 floats
    for (int j = tid; j < GT * TY * (TX / 4); j += 256) {
        int row = j >> 4;                 // k*TY + yy
        int col = j & 15;
        int k  = row >> 3;                // /TY
        int yy = row & (TY - 1);
        int off = ((b * GT + k) * GH + (y0 + yy)) * (GW / 4) + (x0 >> 2) + col;
        __builtin_nontemporal_store(t4[j], &o4[off]);   // write-once, skip L2 pollution
    }
}

// ---------------- Phase 3: replay overflow events (normally zero) ----------------
__global__ __launch_bounds__(256) void k_overflow(
    const uint2* __restrict__ ovf, const unsigned* __restrict__ cnt,
    float* __restrict__ out)
{
    unsigned n = min(cnt[NBINS], OVF_CAP);
    for (unsigned i = blockIdx.x * blockDim.x + threadIdx.x; i < n;
         i += gridDim.x * blockDim.x) {
        uint2 r = ovf[i];
        int x  = r.x & 2047;
        int y  = (r.x >> 11) & 1023;
        int p  = (r.x >> 21) & 1;
        int k0 = (r.x >> 22) & 31;
        int b  = (r.x >> 27) & 7;
        float w1 = __uint_as_float(r.y);
        float w0 = 1.0f - w1;
        float pol = p ? 1.0f : -1.0f;
        int k1 = min(k0 + 1, GT - 1);
        atomicAdd(&out[((b * GT + k0) * GH + y) * GW + x], pol * w0);
        atomicAdd(&out[((b * GT + k1) * GH + y) * GW + x], pol * w1);
    }
}

// ---------------- Fallback (round-1 path) ----------------
__global__ __launch_bounds__(256) void ev2voxel_scatter(
    const float4* __restrict__ ev, const int* __restrict__ counts,
    float* __restrict__ out)
{
    int i = blockIdx.x * blockDim.x + threadIdx.x;
    if (i >= GB * NEV) return;
    int b = i / NEV;
    int n = i - b * NEV;
    if (n >= counts[b]) return;
    float4 e = ev[i];
    int x = min(max((int)e.x, 0), GW - 1);
    int y = min(max((int)e.y, 0), GH - 1);
    float pol = e.w * 2.0f - 1.0f;
    float tb = e.z * (float)(GT - 1);
    int k0 = (int)floorf(tb);
    float w1 = tb - (float)k0;
    float w0 = 1.0f - w1;
    int k0c = min(max(k0, 0), GT - 1);
    int k1c = min(max(k0 + 1, 0), GT - 1);
    int rowbase = (b * GT) * GH;
    atomicAdd(&out[(rowbase + k0c * GH + y) * GW + x], pol * w0);
    atomicAdd(&out[(rowbase + k1c * GH + y) * GW + x], pol * w1);
}

extern "C" void kernel_launch(void* const* d_in, const int* in_sizes, int n_in,
                              void* d_out, int out_size, void* d_ws, size_t ws_size,
                              hipStream_t stream) {
    const float4* ev = (const float4*)d_in[0];   // (B, N, 4) fp32
    const int* counts = (const int*)d_in[1];     // (B,) int
    float* out = (float*)d_out;                  // (B, T, H, W) fp32

    // workspace layout (u32 units): cnt[NBINS] + ovfcnt[1], pad to 8B,
    // buckets[NBINS*CAP] uint2, ovf[OVF_CAP] uint2
    size_t bucket_off = NBINS + 1;
    if (bucket_off & 1) bucket_off++;
    const size_t ovf_off = bucket_off + (size_t)NBINS * CAP * 2;   // in u32
    const size_t need_bytes = (ovf_off + (size_t)OVF_CAP * 2) * 4;

    const int total = GB * NEV;
    const int block = 256;
    const int grid = (total + block - 1) / block;

    if (ws_size < need_bytes) {
        (void)hipMemsetAsync(out, 0, (size_t)out_size * sizeof(float), stream);
        ev2voxel_scatter<<<grid, block, 0, stream>>>(ev, counts, out);
        return;
    }

    unsigned* ws = (unsigned*)d_ws;
    unsigned* cnt = ws;                              // NBINS + 1 (ovf counter)
    uint2* buckets = (uint2*)(ws + bucket_off);
    uint2* ovf     = (uint2*)(ws + ovf_off);

    k_zero<<<(NBINS + 1 + 255) / 256, 256, 0, stream>>>(cnt);
    k_bucket<<<grid, block, 0, stream>>>(ev, counts, cnt, buckets, ovf);
    k_accum<<<NBINS, 256, 0, stream>>>(buckets, cnt, out);
    k_overflow<<<64, 256, 0, stream>>>(ovf, cnt, out);
}

// Round 7
// 305.173 us; speedup vs baseline: 1.3664x; 1.3664x over previous
//
#include <hip/hip_runtime.h>

// Problem constants (match reference setup_inputs)
#define GH 720
#define GW 1280
#define GT 20
#define GB 8
#define NEV 500000

// Spatial tile: TY rows x TX cols, full T depth -> 20*4*64*4B = 20 KB LDS
#define TY 4
#define TX 64
#define NTY (GH / TY)            // 180
#define NTX (GW / TX)            // 20
#define NBINS (GB * NTY * NTX)   // 28800
#define R 4                      // counter replicas per bin (atomic de-contention)
#define SLICE 128                // bucket slots per replica
#define CAP (R * SLICE)          // 512 slots per bin total
#define ILP 4                    // events per thread in k_bucket
#define OVF_CAP (1u << 20)

typedef float vfloat4 __attribute__((ext_vector_type(4)));   // clang vector for nontemporal builtins

// ---------------- Phase 0: zero bin counters + overflow counter ----------------
__global__ __launch_bounds__(256) void k_zero(unsigned* __restrict__ cnt)
{
    int i = blockIdx.x * blockDim.x + threadIdx.x;
    if (i < NBINS * R + 1) cnt[i] = 0u;   // cnt[NBINS*R] is ovfcnt
}

// ---------------- Phase 1: single-pass bucket scatter ----------------
// record: word0 = x | y<<11 | p<<21 | k0c<<22 | b<<27 ; word1 = w1 bits
__global__ __launch_bounds__(256) void k_bucket(
    const float4* __restrict__ ev, const int* __restrict__ counts,
    unsigned* __restrict__ cnt, uint2* __restrict__ buckets,
    uint2* __restrict__ ovf)
{
    const unsigned rep = blockIdx.x & (R - 1);
    int base = blockIdx.x * (256 * ILP) + threadIdx.x;

#pragma unroll
    for (int j = 0; j < ILP; j++) {
        int i = base + j * 256;
        if (i >= GB * NEV) continue;
        int b = i / NEV;                    // constant divisor -> magic-mul
        int n = i - b * NEV;
        if (n >= counts[b]) continue;

        float4 e = ev[i];
        int x = min(max((int)e.x, 0), GW - 1);
        int y = min(max((int)e.y, 0), GH - 1);
        int bin = (b * NTY + (y >> 2)) * NTX + (x >> 6);

        float tb = e.z * (float)(GT - 1);
        int k0 = (int)floorf(tb);
        float w1 = tb - (float)k0;          // before clamping, matches reference
        int k0c = min(max(k0, 0), GT - 1);
        unsigned p = (e.w > 0.5f) ? 1u : 0u;

        unsigned word0 = (unsigned)x | ((unsigned)y << 11) | (p << 21)
                       | ((unsigned)k0c << 22) | ((unsigned)b << 27);
        uint2 rec = make_uint2(word0, __float_as_uint(w1));

        unsigned pos = atomicAdd(&cnt[bin * R + rep], 1u);
        if (pos < SLICE) {
            buckets[(size_t)bin * CAP + rep * SLICE + pos] = rec;
        } else {
            unsigned o = atomicAdd(&cnt[NBINS * R], 1u);
            if (o < OVF_CAP) ovf[o] = rec;
        }
    }
}

// ---------------- Phase 2: per-tile LDS accumulate + full-tile write ----------------
__global__ __launch_bounds__(256) void k_accum(
    const uint2* __restrict__ buckets, const unsigned* __restrict__ cnt,
    float* __restrict__ out)
{
    __shared__ float tile[GT * TY * TX];     // 5120 floats = 20 KB
    int bin = blockIdx.x;
    int tid = threadIdx.x;

    vfloat4* t4z = (vfloat4*)tile;
    for (int j = tid; j < GT * TY * (TX / 4); j += 256) t4z[j] = (vfloat4){0.f, 0.f, 0.f, 0.f};
    __syncthreads();

    const uint2* bp = buckets + (size_t)bin * CAP;
#pragma unroll
    for (int rep = 0; rep < R; rep++) {
        unsigned m = min(cnt[bin * R + rep], (unsigned)SLICE);
        for (unsigned idx = tid; idx < m; idx += 256) {
            uint2 r = bp[rep * SLICE + idx];
            int x  = r.x & 2047;
            int y  = (r.x >> 11) & 1023;
            int p  = (r.x >> 21) & 1;
            int k0 = (r.x >> 22) & 31;
            float w1 = __uint_as_float(r.y);
            float w0 = 1.0f - w1;
            float pol = p ? 1.0f : -1.0f;
            int k1 = min(k0 + 1, GT - 1);
            int yy = y & (TY - 1);
            int xx = x & (TX - 1);
            atomicAdd(&tile[(k0 * TY + yy) * TX + xx], pol * w0);
            atomicAdd(&tile[(k1 * TY + yy) * TX + xx], pol * w1);
        }
    }
    __syncthreads();

    // decompose bin -> (b, ty, tx)
    int tx = bin % NTX;
    int rem = bin / NTX;
    int ty = rem % NTY;
    int b  = rem / NTY;
    int y0 = ty * TY;
    int x0 = tx * TX;

    const vfloat4* t4 = (const vfloat4*)tile;
    vfloat4* o4 = (vfloat4*)out;
    // 1280 float4 per tile; 16 float4 per (k,yy) row of 64 floats
    for (int j = tid; j < GT * TY * (TX / 4); j += 256) {
        int row = j >> 4;                 // k*TY + yy
        int col = j & 15;
        int k  = row >> 2;                // /TY
        int yy = row & (TY - 1);
        int off = ((b * GT + k) * GH + (y0 + yy)) * (GW / 4) + (x0 >> 2) + col;
        __builtin_nontemporal_store(t4[j], &o4[off]);   // write-once, skip L2 pollution
    }
}

// ---------------- Phase 3: replay overflow events (normally zero) ----------------
__global__ __launch_bounds__(256) void k_overflow(
    const uint2* __restrict__ ovf, const unsigned* __restrict__ cnt,
    float* __restrict__ out)
{
    unsigned n = min(cnt[NBINS * R], OVF_CAP);
    for (unsigned i = blockIdx.x * blockDim.x + threadIdx.x; i < n;
         i += gridDim.x * blockDim.x) {
        uint2 r = ovf[i];
        int x  = r.x & 2047;
        int y  = (r.x >> 11) & 1023;
        int p  = (r.x >> 21) & 1;
        int k0 = (r.x >> 22) & 31;
        int b  = (r.x >> 27) & 7;
        float w1 = __uint_as_float(r.y);
        float w0 = 1.0f - w1;
        float pol = p ? 1.0f : -1.0f;
        int k1 = min(k0 + 1, GT - 1);
        atomicAdd(&out[((b * GT + k0) * GH + y) * GW + x], pol * w0);
        atomicAdd(&out[((b * GT + k1) * GH + y) * GW + x], pol * w1);
    }
}

// ---------------- Fallback (round-1 path) ----------------
__global__ __launch_bounds__(256) void ev2voxel_scatter(
    const float4* __restrict__ ev, const int* __restrict__ counts,
    float* __restrict__ out)
{
    int i = blockIdx.x * blockDim.x + threadIdx.x;
    if (i >= GB * NEV) return;
    int b = i / NEV;
    int n = i - b * NEV;
    if (n >= counts[b]) return;
    float4 e = ev[i];
    int x = min(max((int)e.x, 0), GW - 1);
    int y = min(max((int)e.y, 0), GH - 1);
    float pol = e.w * 2.0f - 1.0f;
    float tb = e.z * (float)(GT - 1);
    int k0 = (int)floorf(tb);
    float w1 = tb - (float)k0;
    float w0 = 1.0f - w1;
    int k0c = min(max(k0, 0), GT - 1);
    int k1c = min(max(k0 + 1, 0), GT - 1);
    int rowbase = (b * GT) * GH;
    atomicAdd(&out[(rowbase + k0c * GH + y) * GW + x], pol * w0);
    atomicAdd(&out[(rowbase + k1c * GH + y) * GW + x], pol * w1);
}

extern "C" void kernel_launch(void* const* d_in, const int* in_sizes, int n_in,
                              void* d_out, int out_size, void* d_ws, size_t ws_size,
                              hipStream_t stream) {
    const float4* ev = (const float4*)d_in[0];   // (B, N, 4) fp32
    const int* counts = (const int*)d_in[1];     // (B,) int
    float* out = (float*)d_out;                  // (B, T, H, W) fp32

    // workspace layout (u32 units): cnt[NBINS*R] + ovfcnt[1], pad to 8B,
    // buckets[NBINS*CAP] uint2, ovf[OVF_CAP] uint2
    size_t bucket_off = (size_t)NBINS * R + 1;
    if (bucket_off & 1) bucket_off++;
    const size_t ovf_off = bucket_off + (size_t)NBINS * CAP * 2;   // in u32
    const size_t need_bytes = (ovf_off + (size_t)OVF_CAP * 2) * 4;

    const int total = GB * NEV;
    const int block = 256;

    if (ws_size < need_bytes) {
        (void)hipMemsetAsync(out, 0, (size_t)out_size * sizeof(float), stream);
        ev2voxel_scatter<<<(total + block - 1) / block, block, 0, stream>>>(ev, counts, out);
        return;
    }

    unsigned* ws = (unsigned*)d_ws;
    unsigned* cnt = ws;                              // NBINS*R + 1 (ovf counter)
    uint2* buckets = (uint2*)(ws + bucket_off);
    uint2* ovf     = (uint2*)(ws + ovf_off);

    k_zero<<<(NBINS * R + 1 + 255) / 256, 256, 0, stream>>>(cnt);
    k_bucket<<<(total + block * ILP - 1) / (block * ILP), block, 0, stream>>>(ev, counts, cnt, buckets, ovf);
    k_accum<<<NBINS, 256, 0, stream>>>(buckets, cnt, out);
    k_overflow<<<64, 256, 0, stream>>>(ovf, cnt, out);
}

// Round 8
// 189.562 us; speedup vs baseline: 2.1998x; 1.6099x over previous
//
#include <hip/hip_runtime.h>

// Problem constants (match reference setup_inputs)
#define GH 720
#define GW 1280
#define GT 20
#define GB 8
#define NEV 500000
#define TOTAL (GB * NEV)

// Coarse partition: row-band of 8 rows per batch -> (b, y>>3)
#define CY 90                     // GH/8
#define NCOARSE (GB * CY)         // 720
#define CAPC 6144                 // slots/coarse bucket (worst case ~5930 = 500000/90 + 5 sigma)
#define PAD 32                    // u32 stride per counter -> one 128B line each
#define EVB 8192                  // events per k_part block
#define NBLK1 ((TOTAL + EVB - 1) / EVB)   // 489

// Fine tiles for accumulate: 20 t x 8 rows x 64 cols = 40 KB LDS
#define TY 8
#define TX 64
#define NTXB (GW / TX)            // 20
#define NFINE (NCOARSE * NTXB)    // 14400
#define OVF_CAP (1u << 20)

typedef float vfloat4 __attribute__((ext_vector_type(4)));

// ---------------- Phase 0: zero padded coarse counters + overflow counter ----
__global__ __launch_bounds__(256) void k_zero(unsigned* __restrict__ gcnt)
{
    int i = blockIdx.x * blockDim.x + threadIdx.x;
    if (i < NCOARSE * PAD + 1) gcnt[i] = 0u;   // gcnt[NCOARSE*PAD] = ovf counter
}

// ---------------- Phase 1: coarse partition, block-aggregated reservations ----
// record: word0 = x | y<<11 | p<<21 | k0c<<22 | b<<27 ; word1 = w1 bits
__global__ __launch_bounds__(256) void k_part(
    const float4* __restrict__ ev, const int* __restrict__ counts,
    unsigned* __restrict__ gcnt, uint2* __restrict__ buckets,
    uint2* __restrict__ ovf)
{
    __shared__ unsigned hist[NCOARSE];
    __shared__ unsigned lbase[NCOARSE];
    __shared__ unsigned hist2[NCOARSE];
    const int tid = threadIdx.x;
    const int base = blockIdx.x * EVB + tid;

    for (int c = tid; c < NCOARSE; c += 256) { hist[c] = 0u; hist2[c] = 0u; }
    __syncthreads();

    // pass 1: per-block histogram (LDS atomics only)
    for (int j = 0; j < EVB / 256; j++) {
        int i = base + j * 256;
        if (i >= TOTAL) break;
        int b = i / NEV;                    // constant divisor -> magic-mul
        int n = i - b * NEV;
        if (n >= counts[b]) continue;
        float4 e = ev[i];
        int y = min(max((int)e.y, 0), GH - 1);
        atomicAdd(&hist[b * CY + (y >> 3)], 1u);
    }
    __syncthreads();

    // reserve one contiguous range per (block, bucket): ~720 global atomics/block
    for (int c = tid; c < NCOARSE; c += 256) {
        unsigned h = hist[c];
        lbase[c] = h ? atomicAdd(&gcnt[c * PAD], h) : 0u;
    }
    __syncthreads();

    // pass 2: rank in LDS, write record to reserved slot (no global atomic)
    for (int j = 0; j < EVB / 256; j++) {
        int i = base + j * 256;
        if (i >= TOTAL) break;
        int b = i / NEV;
        int n = i - b * NEV;
        if (n >= counts[b]) continue;
        float4 e = ev[i];
        int x = min(max((int)e.x, 0), GW - 1);
        int y = min(max((int)e.y, 0), GH - 1);
        int c = b * CY + (y >> 3);

        float tb = e.z * (float)(GT - 1);
        int k0 = (int)floorf(tb);
        float w1 = tb - (float)k0;          // before clamping, matches reference
        int k0c = min(max(k0, 0), GT - 1);
        unsigned p = (e.w > 0.5f) ? 1u : 0u;

        unsigned word0 = (unsigned)x | ((unsigned)y << 11) | (p << 21)
                       | ((unsigned)k0c << 22) | ((unsigned)b << 27);
        uint2 rec = make_uint2(word0, __float_as_uint(w1));

        unsigned pos = lbase[c] + atomicAdd(&hist2[c], 1u);
        if (pos < CAPC) {
            buckets[(size_t)c * CAPC + pos] = rec;
        } else {
            unsigned o = atomicAdd(&gcnt[NCOARSE * PAD], 1u);
            if (o < OVF_CAP) ovf[o] = rec;
        }
    }
}

// ---------------- Phase 2: per-coarse reorder to fine-bin-contiguous ----------
__global__ __launch_bounds__(256) void k_fine(
    const uint2* __restrict__ buckets, const unsigned* __restrict__ gcnt,
    unsigned* __restrict__ starts_f, unsigned* __restrict__ cnt_f,
    uint2* __restrict__ arr2)
{
    __shared__ uint2 stash[CAPC];          // 48 KB
    __shared__ unsigned fhist[NTXB], foff[NTXB], fh2[NTXB];
    const int c = blockIdx.x;
    const int tid = threadIdx.x;
    if (tid < NTXB) { fhist[tid] = 0u; fh2[tid] = 0u; }
    __syncthreads();

    unsigned m = min(gcnt[c * PAD], (unsigned)CAPC);
    for (unsigned idx = tid; idx < m; idx += 256) {
        uint2 r = buckets[(size_t)c * CAPC + idx];
        stash[idx] = r;
        atomicAdd(&fhist[(r.x & 2047) >> 6], 1u);
    }
    __syncthreads();

    if (tid == 0) {
        unsigned s = 0;
        for (int t = 0; t < NTXB; t++) { foff[t] = s; s += fhist[t]; }
    }
    __syncthreads();

    if (tid < NTXB) {
        starts_f[c * NTXB + tid] = (unsigned)(c * CAPC) + foff[tid];
        cnt_f[c * NTXB + tid]    = fhist[tid];
    }
    for (unsigned idx = tid; idx < m; idx += 256) {
        uint2 r = stash[idx];
        unsigned tx = (r.x & 2047) >> 6;
        unsigned rk = atomicAdd(&fh2[tx], 1u);
        arr2[(size_t)c * CAPC + foff[tx] + rk] = r;
    }
}

// ---------------- Phase 3: per-tile LDS accumulate + full-tile NT write -------
__global__ __launch_bounds__(256) void k_accum(
    const uint2* __restrict__ arr2, const unsigned* __restrict__ starts_f,
    const unsigned* __restrict__ cnt_f, float* __restrict__ out)
{
    __shared__ float tile[GT * TY * TX];     // 10240 floats = 40 KB
    const int f = blockIdx.x;
    const int tid = threadIdx.x;

    vfloat4* t4z = (vfloat4*)tile;
    for (int j = tid; j < GT * TY * (TX / 4); j += 256) t4z[j] = (vfloat4){0.f, 0.f, 0.f, 0.f};
    __syncthreads();

    unsigned s = starts_f[f], m = cnt_f[f];
    for (unsigned idx = tid; idx < m; idx += 256) {
        uint2 r = arr2[s + idx];
        int x  = r.x & 2047;
        int y  = (r.x >> 11) & 1023;
        int p  = (r.x >> 21) & 1;
        int k0 = (r.x >> 22) & 31;
        float w1 = __uint_as_float(r.y);
        float w0 = 1.0f - w1;
        float pol = p ? 1.0f : -1.0f;
        int k1 = min(k0 + 1, GT - 1);
        int yy = y & (TY - 1);
        int xx = x & (TX - 1);
        atomicAdd(&tile[(k0 * TY + yy) * TX + xx], pol * w0);
        atomicAdd(&tile[(k1 * TY + yy) * TX + xx], pol * w1);
    }
    __syncthreads();

    // decompose f -> (b, ty, tx)
    int b   = f / (CY * NTXB);
    int rem = f % (CY * NTXB);
    int ty  = rem / NTXB;
    int tx  = rem % NTXB;
    int y0 = ty * TY;
    int x0 = tx * TX;

    const vfloat4* t4 = (const vfloat4*)tile;
    vfloat4* o4 = (vfloat4*)out;
    // 2560 float4 per tile; 16 float4 per (k,yy) row of 64 floats
    for (int j = tid; j < GT * TY * (TX / 4); j += 256) {
        int row = j >> 4;                 // k*TY + yy
        int col = j & 15;
        int k  = row >> 3;                // /TY
        int yy = row & (TY - 1);
        int off = ((b * GT + k) * GH + (y0 + yy)) * (GW / 4) + (x0 >> 2) + col;
        __builtin_nontemporal_store(t4[j], &o4[off]);   // write-once, skip L2 pollution
    }
}

// ---------------- Phase 4: replay overflow events (normally zero) -------------
__global__ __launch_bounds__(256) void k_overflow(
    const uint2* __restrict__ ovf, const unsigned* __restrict__ gcnt,
    float* __restrict__ out)
{
    unsigned n = min(gcnt[NCOARSE * PAD], OVF_CAP);
    for (unsigned i = blockIdx.x * blockDim.x + threadIdx.x; i < n;
         i += gridDim.x * blockDim.x) {
        uint2 r = ovf[i];
        int x  = r.x & 2047;
        int y  = (r.x >> 11) & 1023;
        int p  = (r.x >> 21) & 1;
        int k0 = (r.x >> 22) & 31;
        int b  = (r.x >> 27) & 7;
        float w1 = __uint_as_float(r.y);
        float w0 = 1.0f - w1;
        float pol = p ? 1.0f : -1.0f;
        int k1 = min(k0 + 1, GT - 1);
        atomicAdd(&out[((b * GT + k0) * GH + y) * GW + x], pol * w0);
        atomicAdd(&out[((b * GT + k1) * GH + y) * GW + x], pol * w1);
    }
}

// ---------------- Fallback (round-1 path) ----------------
__global__ __launch_bounds__(256) void ev2voxel_scatter(
    const float4* __restrict__ ev, const int* __restrict__ counts,
    float* __restrict__ out)
{
    int i = blockIdx.x * blockDim.x + threadIdx.x;
    if (i >= TOTAL) return;
    int b = i / NEV;
    int n = i - b * NEV;
    if (n >= counts[b]) return;
    float4 e = ev[i];
    int x = min(max((int)e.x, 0), GW - 1);
    int y = min(max((int)e.y, 0), GH - 1);
    float pol = e.w * 2.0f - 1.0f;
    float tb = e.z * (float)(GT - 1);
    int k0 = (int)floorf(tb);
    float w1 = tb - (float)k0;
    float w0 = 1.0f - w1;
    int k0c = min(max(k0, 0), GT - 1);
    int k1c = min(max(k0 + 1, 0), GT - 1);
    int rowbase = (b * GT) * GH;
    atomicAdd(&out[(rowbase + k0c * GH + y) * GW + x], pol * w0);
    atomicAdd(&out[(rowbase + k1c * GH + y) * GW + x], pol * w1);
}

extern "C" void kernel_launch(void* const* d_in, const int* in_sizes, int n_in,
                              void* d_out, int out_size, void* d_ws, size_t ws_size,
                              hipStream_t stream) {
    const float4* ev = (const float4*)d_in[0];   // (B, N, 4) fp32
    const int* counts = (const int*)d_in[1];     // (B,) int
    float* out = (float*)d_out;                  // (B, T, H, W) fp32

    // workspace layout (u32 units):
    //   gcnt   [NCOARSE*PAD + PAD]   (padded counters; [NCOARSE*PAD] = ovf count)
    //   starts_f [NFINE], cnt_f [NFINE]
    //   (8B align) buckets [NCOARSE*CAPC] uint2, arr2 [same], ovf [OVF_CAP] uint2
    const size_t gcnt_off   = 0;
    const size_t starts_off = (size_t)NCOARSE * PAD + PAD;
    const size_t cntf_off   = starts_off + NFINE;
    size_t bucket_off       = cntf_off + NFINE;
    if (bucket_off & 1) bucket_off++;
    const size_t arr2_off = bucket_off + (size_t)NCOARSE * CAPC * 2;   // u32 units
    const size_t ovf_off  = arr2_off + (size_t)NCOARSE * CAPC * 2;
    const size_t need_bytes = (ovf_off + (size_t)OVF_CAP * 2) * 4;

    if (ws_size < need_bytes) {
        (void)hipMemsetAsync(out, 0, (size_t)out_size * sizeof(float), stream);
        ev2voxel_scatter<<<(TOTAL + 255) / 256, 256, 0, stream>>>(ev, counts, out);
        return;
    }

    unsigned* ws = (unsigned*)d_ws;
    unsigned* gcnt     = ws + gcnt_off;
    unsigned* starts_f = ws + starts_off;
    unsigned* cnt_f    = ws + cntf_off;
    uint2* buckets = (uint2*)(ws + bucket_off);
    uint2* arr2    = (uint2*)(ws + arr2_off);
    uint2* ovf     = (uint2*)(ws + ovf_off);

    k_zero<<<(NCOARSE * PAD + 1 + 255) / 256, 256, 0, stream>>>(gcnt);
    k_part<<<NBLK1, 256, 0, stream>>>(ev, counts, gcnt, buckets, ovf);
    k_fine<<<NCOARSE, 256, 0, stream>>>(buckets, gcnt, starts_f, cnt_f, arr2);
    k_accum<<<NFINE, 256, 0, stream>>>(arr2, starts_f, cnt_f, out);
    k_overflow<<<64, 256, 0, stream>>>(ovf, gcnt, out);
}